// Round 12
// baseline (680.105 us; speedup 1.0000x reference)
//
#include <hip/hip_runtime.h>
#include <hip/hip_cooperative_groups.h>

namespace cg = cooperative_groups;

#define N_NODES 4096
#define KNN 9
#define CAPS 128                // survivor capacity per row (2 per lane)
#define CAPE 32                 // max edges per node in strided elist
#define THRESH 0.99f

__device__ __forceinline__ bool vi_greater(float av, int aj, float bv, int bj) {
  // order: larger value first; ties -> smaller index first (matches lax.top_k)
  return (av > bv) || (av == bv && aj < bj);
}

// Branch-free node accumulate: 16 unconditional masked loads (elist pre-zeroed
// so every slot holds a valid edge index). Rare cnt>16 tail is serial.
__device__ __forceinline__ float node_acc128(const float* __restrict__ Z,
                                             const int* __restrict__ elist,
                                             int i, int f, int cnt) {
  const int4* el4 = reinterpret_cast<const int4*>(elist + i * CAPE);
  int4 ea = el4[0], eb = el4[1], ec = el4[2], ed = el4[3];
  int e1[16] = {ea.x, ea.y, ea.z, ea.w, eb.x, eb.y, eb.z, eb.w,
                ec.x, ec.y, ec.z, ec.w, ed.x, ed.y, ed.z, ed.w};
  float acc = 0.f;
#pragma unroll
  for (int j = 0; j < 16; ++j) {
    float m = (j < cnt) ? 1.0f : 0.0f;
    acc = fmaf(m, Z[(size_t)e1[j] * 128 + f], acc);
  }
  for (int t = 16; t < cnt; ++t)
    acc += Z[(size_t)elist[i * CAPE + t] * 128 + f];
  return acc;
}

// Edge stage: Z[e,f] = (1/9) * sum_j DV[idx[e][j]]^-1/2 * Y[idx[e][j], f].
// 4 edges per virtual block (one per wave).
template<int F>
__device__ __forceinline__ void es_stage(int G, int bid, int tid,
                                         const float* __restrict__ Y,
                                         const int* __restrict__ idx,
                                         const int* __restrict__ DV,
                                         float* __restrict__ Z,
                                         float* sf, int* si) {
  const int lane = tid & 63, wv = tid >> 6;
  for (int vb = bid; vb < N_NODES / 4; vb += G) {
    __syncthreads();
    if (tid < 4 * KNN) {
      int e = vb * 4 + tid / KNN;
      int r = idx[e * KNN + tid % KNN];
      si[tid] = r;
      sf[tid] = rsqrtf((float)DV[r]);
    }
    __syncthreads();
    int e = vb * 4 + wv;
    float a[F / 64];
#pragma unroll
    for (int q = 0; q < F / 64; ++q) a[q] = 0.f;
#pragma unroll
    for (int j = 0; j < KNN; ++j) {
      int r = si[wv * KNN + j];
      float wgt = sf[wv * KNN + j];
      const float* yr = Y + (size_t)r * F;
#pragma unroll
      for (int q = 0; q < F / 64; ++q)
        a[q] = fmaf(wgt, yr[lane + q * 64], a[q]);
    }
#pragma unroll
    for (int q = 0; q < F / 64; ++q)
      Z[(size_t)e * F + lane + q * 64] = a[q] * (1.0f / 9.0f);
  }
}

// Node-gather + GEMM stage (R10 node_gemm body): 4 rows per virtual block.
template<int FO, bool WRITE_H>
__device__ __forceinline__ void ng_stage(int G, int bid, int tid,
                                         const float* __restrict__ Z,
                                         const int* __restrict__ elist,
                                         const int* __restrict__ DV,
                                         const float* __restrict__ W,
                                         const float* __restrict__ bias,
                                         float* __restrict__ P,
                                         float* __restrict__ Hout,
                                         float* sf) {
  constexpr int RPT = (FO == 128) ? 2 : 4;
  for (int vb = bid; vb < N_NODES / 4; vb += G) {
    int m0 = vb * 4;
    __syncthreads();
#pragma unroll
    for (int c0 = 0; c0 < 512; c0 += 256) {
      int cell = c0 + tid, rr = cell >> 7, f = cell & 127, i = m0 + rr;
      int cnt = DV[i]; if (cnt > CAPE) cnt = CAPE;
      float acc = node_acc128(Z, elist, i, f, cnt);
      acc = fmaxf(acc * rsqrtf((float)DV[i]), 0.f);
      sf[cell] = acc;
      if (WRITE_H) Hout[(size_t)i * 128 + f] = acc;
    }
    __syncthreads();
    const int f = (FO == 128) ? (tid & 127) : tid;
    const int rb = (FO == 128) ? ((tid >> 7) * 2) : 0;
    float acc[RPT];
#pragma unroll
    for (int rr = 0; rr < RPT; ++rr) acc[rr] = 0.f;
    for (int k = 0; k < 128; k += 4) {
      float w0 = W[(size_t)(k + 0) * FO + f];
      float w1 = W[(size_t)(k + 1) * FO + f];
      float w2 = W[(size_t)(k + 2) * FO + f];
      float w3 = W[(size_t)(k + 3) * FO + f];
#pragma unroll
      for (int rr = 0; rr < RPT; ++rr) {
        float4 y = *reinterpret_cast<const float4*>(&sf[(rb + rr) * 128 + k]);
        acc[rr] = fmaf(y.x, w0, fmaf(y.y, w1, fmaf(y.z, w2, fmaf(y.w, w3, acc[rr]))));
      }
    }
    float bb = bias[f];
#pragma unroll
    for (int rr = 0; rr < RPT; ++rr)
      P[(size_t)(m0 + rb + rr) * FO + f] = acc[rr] + bb;
  }
}

// Final stage: x2[i,f] = relu(DV[i]^-1/2 * sum slots), F=256, 1 node per wave.
__device__ __forceinline__ void final_stage(int G, int bid, int tid,
                                            const float* __restrict__ Z,
                                            const int* __restrict__ elist,
                                            const int* __restrict__ DV,
                                            float* __restrict__ out2) {
  const int lane = tid & 63, wv = tid >> 6;
  for (int vb = bid; vb < N_NODES / 4; vb += G) {
    int i = vb * 4 + wv;
    int dv = DV[i];
    int cc = dv > CAPE ? CAPE : dv;
    const int4* el4 = reinterpret_cast<const int4*>(elist + i * CAPE);
    int4 ea = el4[0], eb = el4[1], ec = el4[2], ed = el4[3];
    int e1[16] = {ea.x, ea.y, ea.z, ea.w, eb.x, eb.y, eb.z, eb.w,
                  ec.x, ec.y, ec.z, ec.w, ed.x, ed.y, ed.z, ed.w};
    float a[4] = {0.f, 0.f, 0.f, 0.f};
#pragma unroll
    for (int t = 0; t < 16; ++t) {
      float m = (t < cc) ? 1.0f : 0.0f;
      const float* zr = Z + (size_t)e1[t] * 256;
#pragma unroll
      for (int q = 0; q < 4; ++q) a[q] = fmaf(m, zr[lane + q * 64], a[q]);
    }
    for (int t = 16; t < cc; ++t) {
      const float* zr = Z + (size_t)elist[i * CAPE + t] * 256;
#pragma unroll
      for (int q = 0; q < 4; ++q) a[q] += zr[lane + q * 64];
    }
    float s = rsqrtf((float)dv);
#pragma unroll
    for (int q = 0; q < 4; ++q)
      out2[(size_t)i * 256 + lane + q * 64] = fmaxf(a[q] * s, 0.f);
  }
}

__global__ __launch_bounds__(256, 4) void mega_kernel(
    const float* __restrict__ x, const float* __restrict__ adj,
    const float* __restrict__ W10, const float* __restrict__ b10,
    const float* __restrict__ W11, const float* __restrict__ b11,
    const float* __restrict__ W20, const float* __restrict__ b20,
    const float* __restrict__ W21, const float* __restrict__ b21,
    float* __restrict__ out, int* __restrict__ idx, int* __restrict__ cur,
    int* __restrict__ elist, float* __restrict__ bufP, float* __restrict__ bufZ) {
  cg::grid_group grid = cg::this_grid();
  __shared__ float sf[1024];
  __shared__ int   si[512];

  const int G = gridDim.x, half = G >> 1;
  const int bid = blockIdx.x, tid = threadIdx.x;
  const int lane = tid & 63, wv = tid >> 6;

  float* x1out = out + (size_t)N_NODES * 256;
  float* x2out = x1out + (size_t)N_NODES * 128;

  // ---- S0: [blocks < half] zero cur/elist + gemm1 (x·W10+b10, x-copy)
  //          [blocks >= half] topk -> idx (runs CONCURRENTLY) ----
  if (bid < half) {
    for (int g = bid * 256 + tid; g < N_NODES; g += half * 256) cur[g] = 0;
    for (int g = bid * 256 + tid; g < N_NODES * CAPE; g += half * 256) elist[g] = 0;
    for (int vb = bid; vb < N_NODES / 4; vb += half) {
      int m0 = vb * 4;
      __syncthreads();
      {
        float4 y4 = reinterpret_cast<const float4*>(x + (size_t)m0 * 256)[tid];
        reinterpret_cast<float4*>(sf)[tid] = y4;
        reinterpret_cast<float4*>(out + (size_t)m0 * 256)[tid] = y4;
      }
      __syncthreads();
      const int f = tid & 127, rb = (tid >> 7) * 2;
      float a0 = 0.f, a1 = 0.f;
      for (int k = 0; k < 256; k += 4) {
        float w0 = W10[(k + 0) * 128 + f];
        float w1 = W10[(k + 1) * 128 + f];
        float w2 = W10[(k + 2) * 128 + f];
        float w3 = W10[(k + 3) * 128 + f];
        float4 y0 = *reinterpret_cast<const float4*>(&sf[(rb + 0) * 256 + k]);
        float4 y1 = *reinterpret_cast<const float4*>(&sf[(rb + 1) * 256 + k]);
        a0 = fmaf(y0.x, w0, fmaf(y0.y, w1, fmaf(y0.z, w2, fmaf(y0.w, w3, a0))));
        a1 = fmaf(y1.x, w0, fmaf(y1.y, w1, fmaf(y1.z, w2, fmaf(y1.w, w3, a1))));
      }
      float bb = b10[f];
      bufP[(size_t)(m0 + rb + 0) * 128 + f] = a0 + bb;
      bufP[(size_t)(m0 + rb + 1) * 128 + f] = a1 + bb;
    }
  } else {
    for (int vb = bid - half; vb < N_NODES / 4; vb += (G - half)) {
      const int row = vb * 4 + wv;
      const float4* r4 = reinterpret_cast<const float4*>(adj + (size_t)row * N_NODES);
      float* wval = sf + wv * CAPS;
      int*   widx = si + wv * CAPS;
      const unsigned long long lmask = (1ull << lane) - 1;
      __syncthreads();
      int n = 0;
#pragma unroll 4
      for (int t = 0; t < 16; ++t) {
        float4 f4 = r4[t * 64 + lane];
        float vals[4] = {f4.x, f4.y, f4.z, f4.w};
        int cb = (t * 64 + lane) * 4;
#pragma unroll
        for (int q = 0; q < 4; ++q) {
          bool pred = (vals[q] > THRESH);
          unsigned long long m = __ballot(pred);
          if (pred) {
            int p = n + __popcll(m & lmask);
            if (p < CAPS) { wval[p] = vals[q]; widx[p] = cb + q; }
          }
          n += __popcll(m);
        }
      }
      __syncthreads();
      int outj[KNN];
      if (n >= 9 && n <= CAPS) {
        float v0 = -3.0e38f, v1 = -3.0e38f;
        int c0 = 0x7fffffff, c1 = 0x7fffffff;
        if (lane < n)      { v0 = wval[lane];      c0 = widx[lane]; }
        if (lane + 64 < n) { v1 = wval[lane + 64]; c1 = widx[lane + 64]; }
        if (c0 == row) v0 = -3.3e38f;   // reference zeroes the diagonal
        if (c1 == row) v1 = -3.3e38f;
#pragma unroll
        for (int rnd = 0; rnd < 8; ++rnd) {
          bool first = vi_greater(v0, c0, v1, c1);
          float mv = first ? v0 : v1;
          int   mc = first ? c0 : c1;
#pragma unroll
          for (int d = 1; d < 64; d <<= 1) {
            float ov = __shfl_xor(mv, d);
            int   oc = __shfl_xor(mc, d);
            if (vi_greater(ov, oc, mv, mc)) { mv = ov; mc = oc; }
          }
          outj[rnd] = mc;
          if (c0 == mc) v0 = -3.3e38f;
          if (c1 == mc) v1 = -3.3e38f;
        }
        outj[8] = row;
      } else {
        const float* r = adj + (size_t)row * N_NODES;
        float v[9]; int ji[9];
#pragma unroll
        for (int t = 0; t < 9; ++t) { v[t] = -3.0e38f; ji[t] = 0x7fffffff; }
        for (int t = 0; t < 64; ++t) {
          int ccx = t * 64 + lane;
          float val = (ccx == row) ? 0.0f : r[ccx];
          if (vi_greater(val, ccx, v[8], ji[8])) {
            v[8] = val; ji[8] = ccx;
#pragma unroll
            for (int s = 8; s > 0; --s) {
              if (vi_greater(v[s], ji[s], v[s-1], ji[s-1])) {
                float tv = v[s]; v[s] = v[s-1]; v[s-1] = tv;
                int tj = ji[s]; ji[s] = ji[s-1]; ji[s-1] = tj;
              }
            }
          }
        }
        bool has_center = false;
#pragma unroll
        for (int rnd = 0; rnd < 9; ++rnd) {
          float mv = v[0]; int mj = ji[0];
#pragma unroll
          for (int d = 1; d < 64; d <<= 1) {
            float ov = __shfl_xor(mv, d);
            int   oj = __shfl_xor(mj, d);
            if (vi_greater(ov, oj, mv, mj)) { mv = ov; mj = oj; }
          }
          outj[rnd] = mj;
          has_center = has_center || (mj == row);
          if (ji[0] == mj) {
#pragma unroll
            for (int s = 0; s < 8; ++s) { v[s] = v[s+1]; ji[s] = ji[s+1]; }
            v[8] = -3.0e38f; ji[8] = 0x7fffffff;
          }
        }
        if (!has_center) outj[8] = row;
      }
      if (lane < KNN) idx[row * KNN + lane] = outj[lane];
    }
  }
  grid.sync();

  // ---- Sb: build strided elist + degrees (cur == DV afterwards) ----
  for (int g = bid * 256 + tid; g < N_NODES * KNN; g += G * 256) {
    int node = idx[g];
    int p = atomicAdd(&cur[node], 1);
    if (p < CAPE) elist[node * CAPE + p] = g / KNN;
  }
  grid.sync();

  // ---- layer 1 ----
  es_stage<128>(G, bid, tid, bufP, idx, cur, bufZ, sf, si);
  grid.sync();
  ng_stage<128, false>(G, bid, tid, bufZ, elist, cur, W11, b11, bufP, nullptr, sf);
  grid.sync();
  es_stage<128>(G, bid, tid, bufP, idx, cur, bufZ, sf, si);
  grid.sync();
  // x1 = relu(node gather), fused with layer-2 first GEMM; writes x1out
  ng_stage<128, true>(G, bid, tid, bufZ, elist, cur, W20, b20, bufP, x1out, sf);
  grid.sync();

  // ---- layer 2 ----
  es_stage<128>(G, bid, tid, bufP, idx, cur, bufZ, sf, si);
  grid.sync();
  ng_stage<256, false>(G, bid, tid, bufZ, elist, cur, W21, b21, bufP, nullptr, sf);
  grid.sync();
  es_stage<256>(G, bid, tid, bufP, idx, cur, bufZ, sf, si);
  grid.sync();
  final_stage(G, bid, tid, bufZ, elist, cur, x2out);
}

extern "C" void kernel_launch(void* const* d_in, const int* in_sizes, int n_in,
                              void* d_out, int out_size, void* d_ws, size_t ws_size,
                              hipStream_t stream) {
  const float* x   = (const float*)d_in[0];
  const float* adj = (const float*)d_in[1];
  const float* W10 = (const float*)d_in[2];
  const float* b10 = (const float*)d_in[3];
  const float* W11 = (const float*)d_in[4];
  const float* b11 = (const float*)d_in[5];
  const float* W20 = (const float*)d_in[6];
  const float* b20 = (const float*)d_in[7];
  const float* W21 = (const float*)d_in[8];
  const float* b21 = (const float*)d_in[9];
  float* out = (float*)d_out;

  char* w = (char*)d_ws;
  int*   idx   = (int*)(w + 0);            // 4096*9*4 = 147456
  int*   cur   = (int*)(w + 147456);       // 16384  (doubles as DV)
  int*   elist = (int*)(w + 163840);       // 4096*32*4 = 524288
  float* bufP  = (float*)(w + 688128);     // 4 MB
  float* bufZ  = (float*)(w + 4882432);    // 4 MB

  // cooperative grid size: all blocks must be co-resident
  int perCU = 0;
  if (hipOccupancyMaxActiveBlocksPerMultiprocessor(
          &perCU, (const void*)mega_kernel, 256, 0) != hipSuccess || perCU < 1)
    perCU = 2;
  int cus = 256;
  hipDeviceGetAttribute(&cus, hipDeviceAttributeMultiprocessorCount, 0);
  int grid = perCU * cus;
  if (grid > 1024) grid = 1024;
  grid &= ~1;                 // even halves for the S0 split
  if (grid < 2) grid = 2;

  void* args[] = {(void*)&x, (void*)&adj,
                  (void*)&W10, (void*)&b10, (void*)&W11, (void*)&b11,
                  (void*)&W20, (void*)&b20, (void*)&W21, (void*)&b21,
                  (void*)&out, (void*)&idx, (void*)&cur, (void*)&elist,
                  (void*)&bufP, (void*)&bufZ};
  hipLaunchCooperativeKernel((void*)mega_kernel, dim3(grid), dim3(256),
                             args, 0, stream);
}

// Round 13
// 125.379 us; speedup vs baseline: 5.4244x; 5.4244x over previous
//
#include <hip/hip_runtime.h>

#define N_NODES 4096
#define KNN 9
#define CAPS 128                // topk survivor capacity per row (2 per lane)
#define CAPE 32                 // max edges per node in strided elist
#define NSTG 16                 // edges staged per node (tail loop beyond)
#define THRESH 0.99f

__device__ __forceinline__ bool vi_greater(float av, int aj, float bv, int bj) {
  // order: larger value first; ties -> smaller index first (matches lax.top_k)
  return (av > bv) || (av == bv && aj < bj);
}

// Dense P1 = x @ W10 + b10 (KD=256, FO=128, ROWS=4, 1024 blocks). Also zeroes
// the edge cursors (runs before topk) and emits the out=x passthrough copy.
__global__ __launch_bounds__(256) void gemm_first(const float* __restrict__ Y,
                                                  const float* __restrict__ W,
                                                  const float* __restrict__ bias,
                                                  float* __restrict__ P,
                                                  float* __restrict__ xcopy,
                                                  int* __restrict__ cur) {
  constexpr int KD = 256, FO = 128, ROWS = 4;
  __shared__ float ylds[ROWS * KD];
  int gid = blockIdx.x * 256 + threadIdx.x;
  if (gid < N_NODES) cur[gid] = 0;
  int m0 = blockIdx.x * ROWS;
  for (int t = threadIdx.x; t < ROWS * KD / 4; t += 256) {
    float4 y4 = reinterpret_cast<const float4*>(Y + (size_t)m0 * KD)[t];
    reinterpret_cast<float4*>(ylds)[t] = y4;
    reinterpret_cast<float4*>(xcopy + (size_t)m0 * KD)[t] = y4;
  }
  __syncthreads();
  const int f  = threadIdx.x & 127;
  const int rb = (threadIdx.x >> 7) * 2;
  float acc[2] = {0.f, 0.f};
  for (int k = 0; k < KD; k += 4) {
    float w0 = W[(size_t)(k + 0) * FO + f];
    float w1 = W[(size_t)(k + 1) * FO + f];
    float w2 = W[(size_t)(k + 2) * FO + f];
    float w3 = W[(size_t)(k + 3) * FO + f];
#pragma unroll
    for (int rr = 0; rr < 2; ++rr) {
      float4 y = *reinterpret_cast<const float4*>(&ylds[(rb + rr) * KD + k]);
      acc[rr] = fmaf(y.x, w0, fmaf(y.y, w1, fmaf(y.z, w2, fmaf(y.w, w3, acc[rr]))));
    }
  }
  float bb = bias[f];
#pragma unroll
  for (int rr = 0; rr < 2; ++rr)
    P[(size_t)(m0 + rb + rr) * FO + f] = acc[rr] + bb;
}

// Top-k (R10-proven): one wave per row, ballot-compaction + 8 argmax rounds,
// exact full-row fallback. Lanes 0..8 write idx and append edge `row` to each
// member's strided elist (cur doubles as node degree DV). cur zeroed upstream.
__global__ __launch_bounds__(256) void topk_kernel(const float* __restrict__ dis,
                                                   int* __restrict__ idx,
                                                   int* __restrict__ cur,
                                                   int* __restrict__ elist) {
  __shared__ float sval[4 * CAPS];
  __shared__ int   sidx[4 * CAPS];
  const int lane = threadIdx.x & 63;
  const int wv = threadIdx.x >> 6;
  const int row = blockIdx.x * 4 + wv;
  const float4* r4 = reinterpret_cast<const float4*>(dis + (size_t)row * N_NODES);
  float* wval = sval + wv * CAPS;
  int*   widx = sidx + wv * CAPS;
  const unsigned long long lmask = (1ull << lane) - 1;

  int n = 0;
#pragma unroll 4
  for (int t = 0; t < 16; ++t) {
    float4 f4 = r4[t * 64 + lane];
    float vals[4] = {f4.x, f4.y, f4.z, f4.w};
    int cb = (t * 64 + lane) * 4;
#pragma unroll
    for (int q = 0; q < 4; ++q) {
      int cc = cb + q;
      bool pred = (vals[q] > THRESH) && (cc != row);
      unsigned long long m = __ballot(pred);
      if (pred) {
        int p = n + __popcll(m & lmask);
        if (p < CAPS) { wval[p] = vals[q]; widx[p] = cc; }
      }
      n += __popcll(m);
    }
  }
  __syncthreads();

  int outj[KNN];
  if (n >= 8 && n <= CAPS) {
    float v0 = -3.0e38f, v1 = -3.0e38f;
    int c0 = 0x7fffffff, c1 = 0x7fffffff;
    if (lane < n)      { v0 = wval[lane];      c0 = widx[lane]; }
    if (lane + 64 < n) { v1 = wval[lane + 64]; c1 = widx[lane + 64]; }
#pragma unroll
    for (int rnd = 0; rnd < 8; ++rnd) {
      bool first = vi_greater(v0, c0, v1, c1);
      float mv = first ? v0 : v1;
      int   mc = first ? c0 : c1;
#pragma unroll
      for (int d = 1; d < 64; d <<= 1) {
        float ov = __shfl_xor(mv, d);
        int   oc = __shfl_xor(mc, d);
        if (vi_greater(ov, oc, mv, mc)) { mv = ov; mc = oc; }
      }
      outj[rnd] = mc;
      if (c0 == mc) v0 = -3.3e38f;
      if (c1 == mc) v1 = -3.3e38f;
    }
    outj[8] = row;
  } else {
    const float* r = dis + (size_t)row * N_NODES;
    float v[9]; int ji[9];
#pragma unroll
    for (int t = 0; t < 9; ++t) { v[t] = -3.0e38f; ji[t] = 0x7fffffff; }
    for (int t = 0; t < 64; ++t) {
      int cc = t * 64 + lane;
      float val = (cc == row) ? 0.0f : r[cc];
      if (vi_greater(val, cc, v[8], ji[8])) {
        v[8] = val; ji[8] = cc;
#pragma unroll
        for (int s = 8; s > 0; --s) {
          if (vi_greater(v[s], ji[s], v[s-1], ji[s-1])) {
            float tv = v[s]; v[s] = v[s-1]; v[s-1] = tv;
            int tj = ji[s]; ji[s] = ji[s-1]; ji[s-1] = tj;
          }
        }
      }
    }
    bool has_center = false;
#pragma unroll
    for (int rnd = 0; rnd < 9; ++rnd) {
      float mv = v[0]; int mj = ji[0];
#pragma unroll
      for (int d = 1; d < 64; d <<= 1) {
        float ov = __shfl_xor(mv, d);
        int   oj = __shfl_xor(mj, d);
        if (vi_greater(ov, oj, mv, mj)) { mv = ov; mj = oj; }
      }
      outj[rnd] = mj;
      has_center = has_center || (mj == row);
      if (ji[0] == mj) {
#pragma unroll
        for (int s = 0; s < 8; ++s) { v[s] = v[s+1]; ji[s] = ji[s+1]; }
        v[8] = -3.0e38f; ji[8] = 0x7fffffff;
      }
    }
    if (!has_center) outj[8] = row;
  }

  if (lane < KNN) {
    int j = outj[lane];
    idx[row * KNN + lane] = j;
    int p = atomicAdd(&cur[j], 1);
    if (p < CAPE) elist[j * CAPE + p] = row;
  }
}

// ---- Recompute-fused G-apply. Per block: 4 nodes. Stage each node's <=16
// edges x 9 members as (row, weight) int2 pairs in LDS (weight=0 for masked
// slots -> no elist zeroing needed), then per cell (node,f) accumulate 144
// coalesced Y loads. Also accumulates rsum = sum of weights (r_i = G row sum).
struct GnodeLds {
  int2  srw[4][NSTG * KNN];   // (row, weight-bits)
  int   se[4][NSTG];
  float sdvi[4];
  int   scnt[4];
  float ylds[4 * 128];        // S rows for GEMM phase / scratch
  float rlds[4];
};

__device__ __forceinline__ void gnode_stage(GnodeLds& L, int m0, int tid,
                                            const int* __restrict__ idx,
                                            const int* __restrict__ elist,
                                            const int* __restrict__ DV) {
  if (tid < 4 * NSTG) {
    int rr = tid >> 4, t = tid & (NSTG - 1);
    int i = m0 + rr;
    int dv = DV[i];
    int cnt = dv < NSTG ? dv : NSTG;
    int e = elist[i * CAPE + t];
    L.se[rr][t] = (t < cnt) ? e : -1;
    if (t == 0) {
      L.sdvi[rr] = rsqrtf((float)dv);
      L.scnt[rr] = dv < CAPE ? dv : CAPE;
    }
  }
  __syncthreads();
  for (int q = tid; q < 4 * NSTG * KNN; q += 256) {
    int rr = q / (NSTG * KNN), rem = q % (NSTG * KNN);
    int e = L.se[rr][rem / KNN];
    int r = (e >= 0) ? idx[e * KNN + rem % KNN] : 0;
    float wgt = (e >= 0) ? rsqrtf((float)DV[r]) : 0.f;
    L.srw[rr][rem] = make_int2(r, __float_as_int(wgt));
  }
  __syncthreads();
}

// Accumulate S[i,f] (pre-scaled) and r_i for one cell. rr uniform per wave.
__device__ __forceinline__ void gnode_acc(const GnodeLds& L, int m0, int rr,
                                          int f, const float* __restrict__ Y,
                                          const int* __restrict__ idx,
                                          const int* __restrict__ elist,
                                          const int* __restrict__ DV,
                                          float& Sv, float& rv) {
  float acc = 0.f, racc = 0.f;
#pragma unroll 12
  for (int q = 0; q < NSTG * KNN; ++q) {
    int2 p = L.srw[rr][q];
    float wq = __int_as_float(p.y);
    acc = fmaf(wq, Y[(size_t)p.x * 128 + f], acc);
    racc += wq;
  }
  int cntf = L.scnt[rr];
  for (int t = NSTG; t < cntf; ++t) {       // rare tail (~1% of nodes)
    int e = elist[(m0 + rr) * CAPE + t];
#pragma unroll
    for (int j = 0; j < KNN; ++j) {
      int r = idx[e * KNN + j];
      float wq = rsqrtf((float)DV[r]);
      acc = fmaf(wq, Y[(size_t)r * 128 + f], acc);
      racc += wq;
    }
  }
  float s = L.sdvi[rr] * (1.0f / 9.0f);
  Sv = acc * s;
  rv = racc * s;
}

// g1: H = relu(G @ Y)  (width 128)
__global__ __launch_bounds__(256) void gnode_relu(const float* __restrict__ Y,
                                                  const int* __restrict__ idx,
                                                  const int* __restrict__ elist,
                                                  const int* __restrict__ DV,
                                                  float* __restrict__ H) {
  __shared__ GnodeLds L;
  int m0 = blockIdx.x * 4, tid = threadIdx.x;
  gnode_stage(L, m0, tid, idx, elist, DV);
#pragma unroll
  for (int c0 = 0; c0 < 512; c0 += 256) {
    int cell = c0 + tid, rr = cell >> 7, f = cell & 127;
    float Sv, rv;
    gnode_acc(L, m0, rr, f, Y, idx, elist, DV, Sv, rv);
    H[(size_t)(m0 + rr) * 128 + f] = fmaxf(Sv, 0.f);
  }
}

// g2/g3/g4: P = relu( (G @ Y) W + r b )  — GEMM fused after the G-apply.
template<int FO>
__global__ __launch_bounds__(256) void gnode_gemm(const float* __restrict__ Y,
                                                  const int* __restrict__ idx,
                                                  const int* __restrict__ elist,
                                                  const int* __restrict__ DV,
                                                  const float* __restrict__ W,
                                                  const float* __restrict__ bias,
                                                  float* __restrict__ P) {
  constexpr int RPT = (FO == 128) ? 2 : 4;
  __shared__ GnodeLds L;
  int m0 = blockIdx.x * 4, tid = threadIdx.x;
  gnode_stage(L, m0, tid, idx, elist, DV);
#pragma unroll
  for (int c0 = 0; c0 < 512; c0 += 256) {
    int cell = c0 + tid, rr = cell >> 7, f = cell & 127;
    float Sv, rv;
    gnode_acc(L, m0, rr, f, Y, idx, elist, DV, Sv, rv);
    L.ylds[cell] = Sv;
    if (f == 0) L.rlds[rr] = rv;
  }
  __syncthreads();
  const int f  = (FO == 128) ? (tid & 127) : tid;
  const int rb = (FO == 128) ? ((tid >> 7) * 2) : 0;
  float acc[RPT];
#pragma unroll
  for (int rr = 0; rr < RPT; ++rr) acc[rr] = 0.f;
  for (int k = 0; k < 128; k += 4) {
    float w0 = W[(size_t)(k + 0) * FO + f];
    float w1 = W[(size_t)(k + 1) * FO + f];
    float w2 = W[(size_t)(k + 2) * FO + f];
    float w3 = W[(size_t)(k + 3) * FO + f];
#pragma unroll
    for (int rr = 0; rr < RPT; ++rr) {
      float4 y = *reinterpret_cast<const float4*>(&L.ylds[(rb + rr) * 128 + k]);
      acc[rr] = fmaf(y.x, w0, fmaf(y.y, w1, fmaf(y.z, w2, fmaf(y.w, w3, acc[rr]))));
    }
  }
  float bb = bias[f];
#pragma unroll
  for (int rr = 0; rr < RPT; ++rr) {
    float rv = L.rlds[rb + rr];
    P[(size_t)(m0 + rb + rr) * FO + f] = fmaxf(fmaf(rv, bb, acc[rr]), 0.f);
  }
}

extern "C" void kernel_launch(void* const* d_in, const int* in_sizes, int n_in,
                              void* d_out, int out_size, void* d_ws, size_t ws_size,
                              hipStream_t stream) {
  const float* x   = (const float*)d_in[0];
  const float* adj = (const float*)d_in[1];
  const float* W10 = (const float*)d_in[2];
  const float* b10 = (const float*)d_in[3];
  const float* W11 = (const float*)d_in[4];
  const float* b11 = (const float*)d_in[5];
  const float* W20 = (const float*)d_in[6];
  const float* b20 = (const float*)d_in[7];
  const float* W21 = (const float*)d_in[8];
  const float* b21 = (const float*)d_in[9];
  float* out = (float*)d_out;

  char* w = (char*)d_ws;
  int*   idx   = (int*)(w + 0);            // 4096*9*4 = 147456
  int*   cur   = (int*)(w + 147456);       // 16384  (doubles as DV)
  int*   elist = (int*)(w + 163840);       // 4096*32*4 = 524288
  float* bufP  = (float*)(w + 688128);     // 2 MB (P1)
  float* bufH  = (float*)(w + 688128 + 2097152);  // 2 MB (h1 / h2)

  float* x1out = out + (size_t)N_NODES * 256;
  float* x2out = x1out + (size_t)N_NODES * 128;

  // 1: P1 = x W10 + b10 ; zero cur ; out = x
  gemm_first<<<N_NODES / 4, 256, 0, stream>>>(x, W10, b10, bufP, out, cur);
  // 2: hypergraph (idx + strided elist; cur == DV afterwards)
  topk_kernel<<<N_NODES / 4, 256, 0, stream>>>(adj, idx, cur, elist);
  // 3: h1 = relu(G P1)
  gnode_relu<<<N_NODES / 4, 256, 0, stream>>>(bufP, idx, elist, cur, bufH);
  // 4: x1 = relu((G h1) W11 + r b11)
  gnode_gemm<128><<<N_NODES / 4, 256, 0, stream>>>(bufH, idx, elist, cur,
                                                   W11, b11, x1out);
  // 5: h2 = relu((G x1) W20 + r b20)
  gnode_gemm<128><<<N_NODES / 4, 256, 0, stream>>>(x1out, idx, elist, cur,
                                                   W20, b20, bufH);
  // 6: x2 = relu((G h2) W21 + r b21)
  gnode_gemm<256><<<N_NODES / 4, 256, 0, stream>>>(bufH, idx, elist, cur,
                                                   W21, b21, x2out);
}

// Round 14
// 98.369 us; speedup vs baseline: 6.9138x; 1.2746x over previous
//
#include <hip/hip_runtime.h>

#define N_NODES 4096
#define KNN 9
#define CAPS 128                // topk survivor capacity per row (2 per lane)
#define CAPE 32                 // max edges per node in strided elist
#define THRESH 0.99f
#define GEMMB 1024              // gemm block-group size in the s0 hetero kernel

__device__ __forceinline__ bool vi_greater(float av, int aj, float bv, int bj) {
  // order: larger value first; ties -> smaller index first (matches lax.top_k)
  return (av > bv) || (av == bv && aj < bj);
}

// ---- S0: heterogeneous dispatch. Blocks [0,GEMMB): P1 = x W10 + b10, copy
// x to out, zero cur. Blocks [GEMMB, 2*GEMMB): topk -> idx. Fully independent
// halves, no cross-group sync needed.
__global__ __launch_bounds__(256) void s0_kernel(const float* __restrict__ x,
                                                 const float* __restrict__ adj,
                                                 const float* __restrict__ W10,
                                                 const float* __restrict__ b10,
                                                 float* __restrict__ P,
                                                 float* __restrict__ xcopy,
                                                 int* __restrict__ cur,
                                                 int* __restrict__ idx) {
  __shared__ float sf[1024];          // gemm: ylds[4*256] ; topk: sval[4*128]+pad
  __shared__ int   si[512];           // topk: sidx[4*128]
  const int tid = threadIdx.x;

  if (blockIdx.x < GEMMB) {
    // ---------- dense GEMM half ----------
    int gid = blockIdx.x * 256 + tid;
    if (gid < N_NODES) cur[gid] = 0;
    int m0 = blockIdx.x * 4;
    {
      float4 y4 = reinterpret_cast<const float4*>(x + (size_t)m0 * 256)[tid];
      reinterpret_cast<float4*>(sf)[tid] = y4;
      reinterpret_cast<float4*>(xcopy + (size_t)m0 * 256)[tid] = y4;
    }
    __syncthreads();
    const int f  = tid & 127;
    const int rb = (tid >> 7) * 2;
    float a0 = 0.f, a1 = 0.f;
    for (int k = 0; k < 256; k += 4) {
      float w0 = W10[(k + 0) * 128 + f];
      float w1 = W10[(k + 1) * 128 + f];
      float w2 = W10[(k + 2) * 128 + f];
      float w3 = W10[(k + 3) * 128 + f];
      float4 y0 = *reinterpret_cast<const float4*>(&sf[(rb + 0) * 256 + k]);
      float4 y1 = *reinterpret_cast<const float4*>(&sf[(rb + 1) * 256 + k]);
      a0 = fmaf(y0.x, w0, fmaf(y0.y, w1, fmaf(y0.z, w2, fmaf(y0.w, w3, a0))));
      a1 = fmaf(y1.x, w0, fmaf(y1.y, w1, fmaf(y1.z, w2, fmaf(y1.w, w3, a1))));
    }
    float bb = b10[f];
    P[(size_t)(m0 + rb + 0) * 128 + f] = a0 + bb;
    P[(size_t)(m0 + rb + 1) * 128 + f] = a1 + bb;
  } else {
    // ---------- topk half (R10-proven body; writes idx only) ----------
    const int lane = tid & 63, wv = tid >> 6;
    const int row = (blockIdx.x - GEMMB) * 4 + wv;
    const float4* r4 = reinterpret_cast<const float4*>(adj + (size_t)row * N_NODES);
    float* wval = sf + wv * CAPS;
    int*   widx = si + wv * CAPS;
    const unsigned long long lmask = (1ull << lane) - 1;

    int n = 0;
#pragma unroll 4
    for (int t = 0; t < 16; ++t) {
      float4 f4 = r4[t * 64 + lane];
      float vals[4] = {f4.x, f4.y, f4.z, f4.w};
      int cb = (t * 64 + lane) * 4;
#pragma unroll
      for (int q = 0; q < 4; ++q) {
        int cc = cb + q;
        bool pred = (vals[q] > THRESH) && (cc != row);
        unsigned long long m = __ballot(pred);
        if (pred) {
          int p = n + __popcll(m & lmask);
          if (p < CAPS) { wval[p] = vals[q]; widx[p] = cc; }
        }
        n += __popcll(m);
      }
    }
    __syncthreads();

    int outj[KNN];
    if (n >= 8 && n <= CAPS) {
      float v0 = -3.0e38f, v1 = -3.0e38f;
      int c0 = 0x7fffffff, c1 = 0x7fffffff;
      if (lane < n)      { v0 = wval[lane];      c0 = widx[lane]; }
      if (lane + 64 < n) { v1 = wval[lane + 64]; c1 = widx[lane + 64]; }
#pragma unroll
      for (int rnd = 0; rnd < 8; ++rnd) {
        bool first = vi_greater(v0, c0, v1, c1);
        float mv = first ? v0 : v1;
        int   mc = first ? c0 : c1;
#pragma unroll
        for (int d = 1; d < 64; d <<= 1) {
          float ov = __shfl_xor(mv, d);
          int   oc = __shfl_xor(mc, d);
          if (vi_greater(ov, oc, mv, mc)) { mv = ov; mc = oc; }
        }
        outj[rnd] = mc;
        if (c0 == mc) v0 = -3.3e38f;
        if (c1 == mc) v1 = -3.3e38f;
      }
      outj[8] = row;
    } else {
      const float* r = adj + (size_t)row * N_NODES;
      float v[9]; int ji[9];
#pragma unroll
      for (int t = 0; t < 9; ++t) { v[t] = -3.0e38f; ji[t] = 0x7fffffff; }
      for (int t = 0; t < 64; ++t) {
        int cc = t * 64 + lane;
        float val = (cc == row) ? 0.0f : r[cc];
        if (vi_greater(val, cc, v[8], ji[8])) {
          v[8] = val; ji[8] = cc;
#pragma unroll
          for (int s = 8; s > 0; --s) {
            if (vi_greater(v[s], ji[s], v[s-1], ji[s-1])) {
              float tv = v[s]; v[s] = v[s-1]; v[s-1] = tv;
              int tj = ji[s]; ji[s] = ji[s-1]; ji[s-1] = tj;
            }
          }
        }
      }
      bool has_center = false;
#pragma unroll
      for (int rnd = 0; rnd < 9; ++rnd) {
        float mv = v[0]; int mj = ji[0];
#pragma unroll
        for (int d = 1; d < 64; d <<= 1) {
          float ov = __shfl_xor(mv, d);
          int   oj = __shfl_xor(mj, d);
          if (vi_greater(ov, oj, mv, mj)) { mv = ov; mj = oj; }
        }
        outj[rnd] = mj;
        has_center = has_center || (mj == row);
        if (ji[0] == mj) {
#pragma unroll
          for (int s = 0; s < 8; ++s) { v[s] = v[s+1]; ji[s] = ji[s+1]; }
          v[8] = -3.0e38f; ji[8] = 0x7fffffff;
        }
      }
      if (!has_center) outj[8] = row;
    }
    if (lane < KNN) idx[row * KNN + lane] = outj[lane];
  }
}

// D2: build strided inverse list (cur zeroed in s0's gemm half; == DV after).
__global__ void build_elist(const int* __restrict__ idx, int* __restrict__ cur,
                            int* __restrict__ elist) {
  int t = blockIdx.x * blockDim.x + threadIdx.x;
  if (t >= N_NODES * KNN) return;
  int node = idx[t];
  int p = atomicAdd(&cur[node], 1);
  if (p < CAPE) elist[node * CAPE + p] = t / KNN;
}

// Stage A: Z[e,f] = (1/9) * sum_j DV[idx[e][j]]^-1/2 * Y[idx[e][j], f]
template<int F>
__global__ __launch_bounds__(F) void edge_gather(const float* __restrict__ Y,
                                                 const int* __restrict__ idx,
                                                 const int* __restrict__ DV,
                                                 float* __restrict__ Z) {
  __shared__ int er[KNN];
  __shared__ float ew[KNN];
  int e = blockIdx.x;
  if (threadIdx.x < KNN) {
    int r = idx[e * KNN + threadIdx.x];
    er[threadIdx.x] = r;
    ew[threadIdx.x] = rsqrtf((float)DV[r]);
  }
  __syncthreads();
  int f = threadIdx.x;
  float acc = 0.f;
#pragma unroll
  for (int j = 0; j < KNN; ++j)
    acc = fmaf(ew[j], Y[(size_t)er[j] * F + f], acc);
  Z[(size_t)e * F + f] = acc * (1.0f / 9.0f);
}

// Branch-free node accumulate: 16 unconditional masked loads. elist is NOT
// initialized — entries are clamped in-bounds with &(N-1) (poison slots give
// a valid address whose contribution the cndmask zeroes).
template<int KD>
__device__ __forceinline__ float node_acc(const float* __restrict__ Z,
                                          const int* __restrict__ elist,
                                          int i, int f, int cnt) {
  const int4* el4 = reinterpret_cast<const int4*>(elist + i * CAPE);
  int4 ea = el4[0], eb = el4[1], ec = el4[2], ed = el4[3];
  int e1[16] = {ea.x, ea.y, ea.z, ea.w, eb.x, eb.y, eb.z, eb.w,
                ec.x, ec.y, ec.z, ec.w, ed.x, ed.y, ed.z, ed.w};
  float acc = 0.f;
#pragma unroll
  for (int j = 0; j < 16; ++j) {
    float m = (j < cnt) ? 1.0f : 0.0f;
    acc = fmaf(m, Z[(size_t)(e1[j] & (N_NODES - 1)) * KD + f], acc);
  }
  for (int t = 16; t < cnt; ++t)
    acc += Z[(size_t)elist[i * CAPE + t] * KD + f];
  return acc;
}

// Final stage B: out[i,f] = relu(DV[i]^-1/2 * sum of node i's edges)
template<int F>
__global__ __launch_bounds__(F) void node_gather(const float* __restrict__ Z,
                                                 const int* __restrict__ elist,
                                                 const int* __restrict__ DV,
                                                 float* __restrict__ out) {
  int i = blockIdx.x;
  int f = threadIdx.x;
  int cnt = DV[i]; if (cnt > CAPE) cnt = CAPE;
  float acc = node_acc<F>(Z, elist, i, f, cnt);
  out[(size_t)i * F + f] = fmaxf(acc * rsqrtf((float)DV[i]), 0.f);
}

// Fused stage B + GEMM: ROWS=8, 256 threads, 512 blocks (8 waves/CU).
// Halves W L2-traffic vs ROWS=4 (67 MB/GEMM). Gather: 4 branch-free 16-load
// bursts per thread. GEMM: FO=128 -> 2 f-groups x 4 rows; FO=256 -> 8 rows.
template<int FO, bool WRITE_H>
__global__ __launch_bounds__(256) void node_gemm(const float* __restrict__ Z,
                                                 const int* __restrict__ elist,
                                                 const int* __restrict__ DV,
                                                 const float* __restrict__ W,
                                                 const float* __restrict__ bias,
                                                 float* __restrict__ P,
                                                 float* __restrict__ Hout) {
  constexpr int KD = 128;
  constexpr int ROWS = 8;
  constexpr int RPT = (FO == 128) ? 4 : 8;   // rows per thread
  __shared__ float ylds[ROWS * KD];
  int m0 = blockIdx.x * ROWS;
#pragma unroll
  for (int c0 = 0; c0 < ROWS * KD; c0 += 256) {
    int cell = c0 + threadIdx.x;
    int rr = cell >> 7, f = cell & 127;
    int i = m0 + rr;
    int cnt = DV[i]; if (cnt > CAPE) cnt = CAPE;
    float acc = node_acc<KD>(Z, elist, i, f, cnt);
    acc = fmaxf(acc * rsqrtf((float)DV[i]), 0.f);
    ylds[cell] = acc;
    if (WRITE_H) Hout[(size_t)i * KD + f] = acc;
  }
  __syncthreads();
  const int f  = (FO == 128) ? (threadIdx.x & 127) : threadIdx.x;
  const int rb = (FO == 128) ? ((threadIdx.x >> 7) * 4) : 0;
  float acc[RPT];
#pragma unroll
  for (int rr = 0; rr < RPT; ++rr) acc[rr] = 0.f;
  for (int k = 0; k < KD; k += 4) {
    float w0 = W[(size_t)(k + 0) * FO + f];
    float w1 = W[(size_t)(k + 1) * FO + f];
    float w2 = W[(size_t)(k + 2) * FO + f];
    float w3 = W[(size_t)(k + 3) * FO + f];
#pragma unroll
    for (int rr = 0; rr < RPT; ++rr) {
      float4 y = *reinterpret_cast<const float4*>(&ylds[(rb + rr) * KD + k]);
      acc[rr] = fmaf(y.x, w0, fmaf(y.y, w1, fmaf(y.z, w2, fmaf(y.w, w3, acc[rr]))));
    }
  }
  float bb = bias[f];
#pragma unroll
  for (int rr = 0; rr < RPT; ++rr)
    P[(size_t)(m0 + rb + rr) * FO + f] = acc[rr] + bb;
}

extern "C" void kernel_launch(void* const* d_in, const int* in_sizes, int n_in,
                              void* d_out, int out_size, void* d_ws, size_t ws_size,
                              hipStream_t stream) {
  const float* x   = (const float*)d_in[0];
  const float* adj = (const float*)d_in[1];
  const float* W10 = (const float*)d_in[2];
  const float* b10 = (const float*)d_in[3];
  const float* W11 = (const float*)d_in[4];
  const float* b11 = (const float*)d_in[5];
  const float* W20 = (const float*)d_in[6];
  const float* b20 = (const float*)d_in[7];
  const float* W21 = (const float*)d_in[8];
  const float* b21 = (const float*)d_in[9];
  float* out = (float*)d_out;

  char* w = (char*)d_ws;
  int*   idx   = (int*)(w + 0);            // 4096*9*4 = 147456
  int*   cur   = (int*)(w + 147456);       // 16384  (doubles as DV)
  int*   elist = (int*)(w + 163840);       // 4096*32*4 = 524288 (uninitialized)
  float* bufP  = (float*)(w + 688128);     // 4 MB
  float* bufZ  = (float*)(w + 4882432);    // 4 MB

  float* x1out = out + (size_t)N_NODES * 256;
  float* x2out = x1out + (size_t)N_NODES * 128;

  // D1: [gemm_first (P1, x-copy, cur=0)  ||  topk -> idx] — independent halves
  s0_kernel<<<2 * GEMMB, 256, 0, stream>>>(x, adj, W10, b10, bufP, out, cur, idx);
  // D2: inverse edge list (cur becomes DV)
  build_elist<<<(N_NODES * KNN + 255) / 256, 256, 0, stream>>>(idx, cur, elist);

  // layer 1
  edge_gather<128><<<N_NODES, 128, 0, stream>>>(bufP, idx, cur, bufZ);
  node_gemm<128, false><<<N_NODES / 8, 256, 0, stream>>>(bufZ, elist, cur,
                                                         W11, b11, bufP, nullptr);
  edge_gather<128><<<N_NODES, 128, 0, stream>>>(bufP, idx, cur, bufZ);
  // x1 = relu(node gather); fused with layer-2 first GEMM, also writes x1out
  node_gemm<128, true><<<N_NODES / 8, 256, 0, stream>>>(bufZ, elist, cur,
                                                        W20, b20, bufP, x1out);
  // layer 2
  edge_gather<128><<<N_NODES, 128, 0, stream>>>(bufP, idx, cur, bufZ);
  node_gemm<256, false><<<N_NODES / 8, 256, 0, stream>>>(bufZ, elist, cur,
                                                         W21, b21, bufP, nullptr);
  edge_gather<256><<<N_NODES, 256, 0, stream>>>(bufP, idx, cur, bufZ);
  node_gather<256><<<N_NODES, 256, 0, stream>>>(bufZ, elist, cur, x2out);
}

// Round 15
// 93.668 us; speedup vs baseline: 7.2608x; 1.0502x over previous
//
#include <hip/hip_runtime.h>

#define N_NODES 4096
#define KNN 9
#define CAPS 128                // topk survivor capacity per row (2 per lane)
#define CAPE 32                 // max edges per node in strided elist
#define THRESH 0.99f
#define GEMMB 1024              // blocks per half in the s0 hetero kernel

__device__ __forceinline__ bool vi_greater(float av, int aj, float bv, int bj) {
  // order: larger value first; ties -> smaller index first (matches lax.top_k)
  return (av > bv) || (av == bv && aj < bj);
}

// ---- S0: heterogeneous dispatch. Blocks [0,GEMMB): topk -> idx (long pole,
// launched first). Blocks [GEMMB,2*GEMMB): P1 = x W10 + b10, x->out copy,
// zero cur. Fully independent halves, no cross-group sync.
__global__ __launch_bounds__(256) void s0_kernel(const float* __restrict__ x,
                                                 const float* __restrict__ adj,
                                                 const float* __restrict__ W10,
                                                 const float* __restrict__ b10,
                                                 float* __restrict__ P,
                                                 float* __restrict__ xcopy,
                                                 int* __restrict__ cur,
                                                 int* __restrict__ idx) {
  __shared__ float sf[1024];          // topk: 4 wave regions x 128 ; gemm: ylds
  __shared__ int   si[512];           // topk: 4 wave regions x 128
  const int tid = threadIdx.x;

  if (blockIdx.x < GEMMB) {
    // ---------- topk half ----------
    const int lane = tid & 63, wv = tid >> 6;
    const int row = blockIdx.x * 4 + wv;
    const float4* r4 = reinterpret_cast<const float4*>(adj + (size_t)row * N_NODES);
    float* wval = sf + wv * CAPS;
    int*   widx = si + wv * CAPS;
    const unsigned long long lmask = (1ull << lane) - 1;

    // ballot-compaction of survivors > THRESH (diagonal NOT filtered here;
    // handled in the rank phase — saves 1 cmp per element)
    int n = 0;
#pragma unroll 4
    for (int t = 0; t < 16; ++t) {
      float4 f4 = r4[t * 64 + lane];
      float vals[4] = {f4.x, f4.y, f4.z, f4.w};
      int cb = (t * 64 + lane) * 4;
#pragma unroll
      for (int q = 0; q < 4; ++q) {
        bool pred = (vals[q] > THRESH);
        unsigned long long m = __ballot(pred);
        if (pred) {
          int p = n + __popcll(m & lmask);
          if (p < CAPS) { wval[p] = vals[q]; widx[p] = cb + q; }
        }
        n += __popcll(m);
      }
    }
    // per-wave LDS region written and read by the same wave: program order.

    if (n >= 9 && n <= CAPS) {
      // RANK-BASED top-8: candidate rank = #{valid survivors greater}.
      // Broadcast scan over LDS — parallel, no shfl chains. Ranks 0..7 are
      // the top-8; written at deterministic positions (== old extraction
      // order, bit-identical idx). Slot 8 = center node.
      bool val0 = lane < n, val1 = lane + 64 < n;
      float v0 = 0.f, v1 = 0.f; int c0 = -1, c1 = -1;
      if (val0) { v0 = wval[lane];      c0 = widx[lane]; }
      if (val1) { v1 = wval[lane + 64]; c1 = widx[lane + 64]; }
      if (c0 == row) val0 = false;      // reference zeroes the diagonal
      if (c1 == row) val1 = false;
      int r0 = 0, r1 = 0;
      if (n <= 64) {
        for (int s = 0; s < n; ++s) {
          float vs = wval[s]; int cs = widx[s];
          if (cs != row && vi_greater(vs, cs, v0, c0)) ++r0;
        }
      } else {
        for (int s = 0; s < n; ++s) {
          float vs = wval[s]; int cs = widx[s];
          bool d = (cs != row);
          if (d && vi_greater(vs, cs, v0, c0)) ++r0;
          if (d && vi_greater(vs, cs, v1, c1)) ++r1;
        }
      }
      if (val0 && r0 < 8) idx[row * KNN + r0] = c0;
      if (val1 && r1 < 8) idx[row * KNN + r1] = c1;
      if (lane == 0)      idx[row * KNN + 8] = row;
    } else {
      // exact fallback: full-row per-lane sorted top-9 + 9 extraction rounds
      const float* r = adj + (size_t)row * N_NODES;
      float v[9]; int ji[9];
#pragma unroll
      for (int t = 0; t < 9; ++t) { v[t] = -3.0e38f; ji[t] = 0x7fffffff; }
      for (int t = 0; t < 64; ++t) {
        int cc = t * 64 + lane;
        float val = (cc == row) ? 0.0f : r[cc];
        if (vi_greater(val, cc, v[8], ji[8])) {
          v[8] = val; ji[8] = cc;
#pragma unroll
          for (int s = 8; s > 0; --s) {
            if (vi_greater(v[s], ji[s], v[s-1], ji[s-1])) {
              float tv = v[s]; v[s] = v[s-1]; v[s-1] = tv;
              int tj = ji[s]; ji[s] = ji[s-1]; ji[s-1] = tj;
            }
          }
        }
      }
      int o0=0,o1=0,o2=0,o3=0,o4=0,o5=0,o6=0,o7=0,o8=0;
      bool has_center = false;
#pragma unroll
      for (int rnd = 0; rnd < 9; ++rnd) {
        float mv = v[0]; int mj = ji[0];
#pragma unroll
        for (int d = 1; d < 64; d <<= 1) {
          float ov = __shfl_xor(mv, d);
          int   oj = __shfl_xor(mj, d);
          if (vi_greater(ov, oj, mv, mj)) { mv = ov; mj = oj; }
        }
        switch (rnd) {   // static targets (avoid dynamic reg-array indexing)
          case 0: o0 = mj; break; case 1: o1 = mj; break;
          case 2: o2 = mj; break; case 3: o3 = mj; break;
          case 4: o4 = mj; break; case 5: o5 = mj; break;
          case 6: o6 = mj; break; case 7: o7 = mj; break;
          default: o8 = mj; break;
        }
        has_center = has_center || (mj == row);
        if (ji[0] == mj) {
#pragma unroll
          for (int s = 0; s < 8; ++s) { v[s] = v[s+1]; ji[s] = ji[s+1]; }
          v[8] = -3.0e38f; ji[8] = 0x7fffffff;
        }
      }
      if (!has_center) o8 = row;
      if (lane == 0) {
        int* ip = idx + row * KNN;
        ip[0]=o0; ip[1]=o1; ip[2]=o2; ip[3]=o3; ip[4]=o4;
        ip[5]=o5; ip[6]=o6; ip[7]=o7; ip[8]=o8;
      }
    }
  } else {
    // ---------- dense GEMM half ----------
    int bb0 = blockIdx.x - GEMMB;
    int gid = bb0 * 256 + tid;
    if (gid < N_NODES) cur[gid] = 0;
    int m0 = bb0 * 4;
    {
      float4 y4 = reinterpret_cast<const float4*>(x + (size_t)m0 * 256)[tid];
      reinterpret_cast<float4*>(sf)[tid] = y4;
      reinterpret_cast<float4*>(xcopy + (size_t)m0 * 256)[tid] = y4;
    }
    __syncthreads();
    const int f  = tid & 127;
    const int rb = (tid >> 7) * 2;
    float a0 = 0.f, a1 = 0.f;
    for (int k = 0; k < 256; k += 4) {
      float w0 = W10[(k + 0) * 128 + f];
      float w1 = W10[(k + 1) * 128 + f];
      float w2 = W10[(k + 2) * 128 + f];
      float w3 = W10[(k + 3) * 128 + f];
      float4 y0 = *reinterpret_cast<const float4*>(&sf[(rb + 0) * 256 + k]);
      float4 y1 = *reinterpret_cast<const float4*>(&sf[(rb + 1) * 256 + k]);
      a0 = fmaf(y0.x, w0, fmaf(y0.y, w1, fmaf(y0.z, w2, fmaf(y0.w, w3, a0))));
      a1 = fmaf(y1.x, w0, fmaf(y1.y, w1, fmaf(y1.z, w2, fmaf(y1.w, w3, a1))));
    }
    float bb = b10[f];
    P[(size_t)(m0 + rb + 0) * 128 + f] = a0 + bb;
    P[(size_t)(m0 + rb + 1) * 128 + f] = a1 + bb;
  }
}

// D2: build strided inverse list (cur zeroed in s0's gemm half; == DV after).
__global__ void build_elist(const int* __restrict__ idx, int* __restrict__ cur,
                            int* __restrict__ elist) {
  int t = blockIdx.x * blockDim.x + threadIdx.x;
  if (t >= N_NODES * KNN) return;
  int node = idx[t];
  int p = atomicAdd(&cur[node], 1);
  if (p < CAPE) elist[node * CAPE + p] = t / KNN;
}

// Stage A: Z[e,f] = (1/9) * sum_j DV[idx[e][j]]^-1/2 * Y[idx[e][j], f]
template<int F>
__global__ __launch_bounds__(F) void edge_gather(const float* __restrict__ Y,
                                                 const int* __restrict__ idx,
                                                 const int* __restrict__ DV,
                                                 float* __restrict__ Z) {
  __shared__ int er[KNN];
  __shared__ float ew[KNN];
  int e = blockIdx.x;
  if (threadIdx.x < KNN) {
    int r = idx[e * KNN + threadIdx.x];
    er[threadIdx.x] = r;
    ew[threadIdx.x] = rsqrtf((float)DV[r]);
  }
  __syncthreads();
  int f = threadIdx.x;
  float acc = 0.f;
#pragma unroll
  for (int j = 0; j < KNN; ++j)
    acc = fmaf(ew[j], Y[(size_t)er[j] * F + f], acc);
  Z[(size_t)e * F + f] = acc * (1.0f / 9.0f);
}

// Branch-free node accumulate: 16 unconditional masked loads. elist is NOT
// initialized — entries clamped in-bounds with &(N-1); cndmask zeroes poison.
template<int KD>
__device__ __forceinline__ float node_acc(const float* __restrict__ Z,
                                          const int* __restrict__ elist,
                                          int i, int f, int cnt) {
  const int4* el4 = reinterpret_cast<const int4*>(elist + i * CAPE);
  int4 ea = el4[0], eb = el4[1], ec = el4[2], ed = el4[3];
  int e1[16] = {ea.x, ea.y, ea.z, ea.w, eb.x, eb.y, eb.z, eb.w,
                ec.x, ec.y, ec.z, ec.w, ed.x, ed.y, ed.z, ed.w};
  float acc = 0.f;
#pragma unroll
  for (int j = 0; j < 16; ++j) {
    float m = (j < cnt) ? 1.0f : 0.0f;
    acc = fmaf(m, Z[(size_t)(e1[j] & (N_NODES - 1)) * KD + f], acc);
  }
  for (int t = 16; t < cnt; ++t)
    acc += Z[(size_t)elist[i * CAPE + t] * KD + f];
  return acc;
}

// Final stage B: out[i,f] = relu(DV[i]^-1/2 * sum of node i's edges)
template<int F>
__global__ __launch_bounds__(F) void node_gather(const float* __restrict__ Z,
                                                 const int* __restrict__ elist,
                                                 const int* __restrict__ DV,
                                                 float* __restrict__ out) {
  int i = blockIdx.x;
  int f = threadIdx.x;
  int cnt = DV[i]; if (cnt > CAPE) cnt = CAPE;
  float acc = node_acc<F>(Z, elist, i, f, cnt);
  out[(size_t)i * F + f] = fmaxf(acc * rsqrtf((float)DV[i]), 0.f);
}

// Fused stage B + GEMM: ROWS=8, 256 threads, 512 blocks (8 waves/CU).
template<int FO, bool WRITE_H>
__global__ __launch_bounds__(256) void node_gemm(const float* __restrict__ Z,
                                                 const int* __restrict__ elist,
                                                 const int* __restrict__ DV,
                                                 const float* __restrict__ W,
                                                 const float* __restrict__ bias,
                                                 float* __restrict__ P,
                                                 float* __restrict__ Hout) {
  constexpr int KD = 128;
  constexpr int ROWS = 8;
  constexpr int RPT = (FO == 128) ? 4 : 8;   // rows per thread
  __shared__ float ylds[ROWS * KD];
  int m0 = blockIdx.x * ROWS;
#pragma unroll
  for (int c0 = 0; c0 < ROWS * KD; c0 += 256) {
    int cell = c0 + threadIdx.x;
    int rr = cell >> 7, f = cell & 127;
    int i = m0 + rr;
    int cnt = DV[i]; if (cnt > CAPE) cnt = CAPE;
    float acc = node_acc<KD>(Z, elist, i, f, cnt);
    acc = fmaxf(acc * rsqrtf((float)DV[i]), 0.f);
    ylds[cell] = acc;
    if (WRITE_H) Hout[(size_t)i * KD + f] = acc;
  }
  __syncthreads();
  const int f  = (FO == 128) ? (threadIdx.x & 127) : threadIdx.x;
  const int rb = (FO == 128) ? ((threadIdx.x >> 7) * 4) : 0;
  float acc[RPT];
#pragma unroll
  for (int rr = 0; rr < RPT; ++rr) acc[rr] = 0.f;
  for (int k = 0; k < KD; k += 4) {
    float w0 = W[(size_t)(k + 0) * FO + f];
    float w1 = W[(size_t)(k + 1) * FO + f];
    float w2 = W[(size_t)(k + 2) * FO + f];
    float w3 = W[(size_t)(k + 3) * FO + f];
#pragma unroll
    for (int rr = 0; rr < RPT; ++rr) {
      float4 y = *reinterpret_cast<const float4*>(&ylds[(rb + rr) * KD + k]);
      acc[rr] = fmaf(y.x, w0, fmaf(y.y, w1, fmaf(y.z, w2, fmaf(y.w, w3, acc[rr]))));
    }
  }
  float bb = bias[f];
#pragma unroll
  for (int rr = 0; rr < RPT; ++rr)
    P[(size_t)(m0 + rb + rr) * FO + f] = acc[rr] + bb;
}

extern "C" void kernel_launch(void* const* d_in, const int* in_sizes, int n_in,
                              void* d_out, int out_size, void* d_ws, size_t ws_size,
                              hipStream_t stream) {
  const float* x   = (const float*)d_in[0];
  const float* adj = (const float*)d_in[1];
  const float* W10 = (const float*)d_in[2];
  const float* b10 = (const float*)d_in[3];
  const float* W11 = (const float*)d_in[4];
  const float* b11 = (const float*)d_in[5];
  const float* W20 = (const float*)d_in[6];
  const float* b20 = (const float*)d_in[7];
  const float* W21 = (const float*)d_in[8];
  const float* b21 = (const float*)d_in[9];
  float* out = (float*)d_out;

  char* w = (char*)d_ws;
  int*   idx   = (int*)(w + 0);            // 4096*9*4 = 147456
  int*   cur   = (int*)(w + 147456);       // 16384  (doubles as DV)
  int*   elist = (int*)(w + 163840);       // 524288 (uninitialized; clamped)
  float* bufP  = (float*)(w + 688128);     // 4 MB
  float* bufZ  = (float*)(w + 4882432);    // 4 MB

  float* x1out = out + (size_t)N_NODES * 256;
  float* x2out = x1out + (size_t)N_NODES * 128;

  // D1: [topk -> idx  ||  gemm_first (P1, x-copy, cur=0)] — independent halves
  s0_kernel<<<2 * GEMMB, 256, 0, stream>>>(x, adj, W10, b10, bufP, out, cur, idx);
  // D2: inverse edge list (cur becomes DV)
  build_elist<<<(N_NODES * KNN + 255) / 256, 256, 0, stream>>>(idx, cur, elist);

  // layer 1
  edge_gather<128><<<N_NODES, 128, 0, stream>>>(bufP, idx, cur, bufZ);
  node_gemm<128, false><<<N_NODES / 8, 256, 0, stream>>>(bufZ, elist, cur,
                                                         W11, b11, bufP, nullptr);
  edge_gather<128><<<N_NODES, 128, 0, stream>>>(bufP, idx, cur, bufZ);
  // x1 = relu(node gather); fused with layer-2 first GEMM, also writes x1out
  node_gemm<128, true><<<N_NODES / 8, 256, 0, stream>>>(bufZ, elist, cur,
                                                        W20, b20, bufP, x1out);
  // layer 2
  edge_gather<128><<<N_NODES, 128, 0, stream>>>(bufP, idx, cur, bufZ);
  node_gemm<256, false><<<N_NODES / 8, 256, 0, stream>>>(bufZ, elist, cur,
                                                         W21, b21, bufP, nullptr);
  edge_gather<256><<<N_NODES, 256, 0, stream>>>(bufP, idx, cur, bufZ);
  node_gather<256><<<N_NODES, 256, 0, stream>>>(bufZ, elist, cur, x2out);
}